// Round 6
// baseline (184.909 us; speedup 1.0000x reference)
//
#include <hip/hip_runtime.h>
#include <hip/hip_fp16.h>
#include <math.h>

#define CC 64
#define KK 16
#define NNODES 15
#define DD 512      // input feature dim
#define MM 512      // output dim
#define NN 16384    // rows

#define TR 128      // rows per decode block
#define TM 128      // m per decode block
#define CHUNK 8     // c's staged per LDS buffer (8 * 16 * 128 fp16 = 32 KB)

// ---------------------------------------------------------------------------
// XLA/Eigen fast-tanh for f32 (bit-exact vs JAX's jnp.tanh lowering).
// Round 3/4/5 evidence: this is required to match the golden's argmax codes.
// ---------------------------------------------------------------------------
__device__ __forceinline__ float xla_tanhf(float x) {
    const float kMax = 7.90531110763549805f;
    bool tiny = fabsf(x) < 0.0004f;
    float xc = fminf(fmaxf(x, -kMax), kMax);
    float x2 = __fmul_rn(xc, xc);
    float p = __fmaf_rn(x2, -2.76076847742355e-16f, 2.00018790482477e-13f);
    p = __fmaf_rn(x2, p, -8.60467152213735e-11f);
    p = __fmaf_rn(x2, p, 5.12229709037114e-08f);
    p = __fmaf_rn(x2, p, 1.48572235717979e-05f);
    p = __fmaf_rn(x2, p, 6.37261928875436e-04f);
    p = __fmaf_rn(x2, p, 4.89352455891786e-03f);
    p = __fmul_rn(xc, p);
    float q = __fmaf_rn(x2, 1.19825839466702e-06f, 1.18534705686654e-04f);
    q = __fmaf_rn(x2, q, 2.26843463243900e-03f);
    q = __fmaf_rn(x2, q, 4.89352518554385e-03f);
    return tiny ? x : __fdiv_rn(p, q);
}

// ---------------------------------------------------------------------------
// Kernel 1: transpose L (M, C*K) fp32 -> Lt16 (C*K, M) fp16.
// Reads coalesced over ck; scattered 2B writes are absorbed by L2 (2 MB out).
// fp16 LUT halves decode LDS/L2 traffic; rounding error ~0.03 max (budget 0.7).
// ---------------------------------------------------------------------------
__global__ __launch_bounds__(256) void transpose_lut16(const float* __restrict__ L,
                                                       __half* __restrict__ Lt) {
    int gid = blockIdx.x * 256 + threadIdx.x;   // over C*K*M = 524288
    int ck = gid & 1023;
    int m  = gid >> 10;
    Lt[(size_t)ck * MM + m] = __float2half(L[(size_t)m * (CC * KK) + ck]);
}

// ---------------------------------------------------------------------------
// Kernel 2: encode — UNCHANGED from round 5 (bit-exact codes verified).
// ---------------------------------------------------------------------------
__global__ __launch_bounds__(256) void encode_kernel(const float* __restrict__ I,
                                                     const float* __restrict__ A,
                                                     const float* __restrict__ T,
                                                     unsigned char* __restrict__ idx) {
    __shared__ float sA[CC * 8 * 4];   // 2048 floats
    __shared__ float sT[CC * NNODES];  // 960 floats
    int tid = threadIdx.x;
    for (int i = tid; i < CC * 32; i += 256) sA[i] = A[i];
    for (int i = tid; i < CC * NNODES; i += 256) sT[i] = T[i];
    __syncthreads();

    int gid = blockIdx.x * 256 + tid;   // 0 .. N*C-1
    int j = gid >> 6;
    int c = gid & 63;

    const float* Ij = I + (size_t)j * DD + c * 8;
    float4 v0 = ((const float4*)Ij)[0];
    float4 v1 = ((const float4*)Ij)[1];
    float iv[8] = {v0.x, v0.y, v0.z, v0.w, v1.x, v1.y, v1.z, v1.w};

    float t[4] = {0.f, 0.f, 0.f, 0.f};
#pragma unroll
    for (int s = 0; s < 8; ++s) {
        float v = iv[s];
#pragma unroll
        for (int d = 0; d < 4; ++d)
            t[d] = __fmaf_rn(v, sA[c * 32 + s * 4 + d], t[d]);
    }

    const int lvl[NNODES] = {0, 1, 1, 2, 2, 2, 2, 3, 3, 3, 3, 3, 3, 3, 3};
    float th[NNODES];
#pragma unroll
    for (int i = 0; i < NNODES; ++i) {
        float h = __fsub_rn(t[lvl[i]], sT[c * NNODES + i]);
        th[i] = xla_tanhf(h);
    }

    int best = 0;
    float bestv = -3.0e38f;
#pragma unroll
    for (int k = 0; k < KK; ++k) {
        int node = 0;
        float s = 0.f;
#pragma unroll
        for (int l = 0; l < 4; ++l) {
            int bit = (k >> (3 - l)) & 1;
            s = __fadd_rn(s, bit ? th[node] : -th[node]);
            node = 2 * node + 1 + bit;
        }
        if (s > bestv) { bestv = s; best = k; }   // strict >: first-max
    }
    idx[gid] = (unsigned char)best;
}

// ---------------------------------------------------------------------------
// Kernel 3: decode v2 — 128-row x 128-m tile, LDS-staged fp16 LUT.
// L2 LUT traffic: 2.15 GB -> 128 MB (reuse 2 -> 128 rows). Gathers served
// from LDS (1.07 GB fp16, conflict-free ds_read_b64). Double-buffered 8-c
// chunks; prefetch into regs overlaps global latency with compute.
// Accumulation stays fp32, c ascending (same order as the passing round 5).
// ---------------------------------------------------------------------------
__global__ __launch_bounds__(256) void decode_kernel(const unsigned char* __restrict__ idx,
                                                     const __half* __restrict__ Lt,
                                                     float* __restrict__ out) {
    __shared__ unsigned char sCode[CC * 144];        // [c][r], stride 144 (16B-aligned, conflict-broken)
    __shared__ __half sL[2][CHUNK * KK * TM];        // 2 x 32 KB

    const int tid   = threadIdx.x;
    const int mtile = blockIdx.x & 3;
    const int rtile = blockIdx.x >> 2;
    const int j0 = rtile * TR;
    const int m0 = mtile * TM;

    // ---- stage codes transposed: sCode[c][r] = idx[(j0+r)*64 + c]
    {
        int c  = tid & 63;
        int r0 = (tid >> 6) * 32;
        const unsigned char* g = idx + (size_t)(j0 + r0) * CC + c;  // coalesced per i
#pragma unroll
        for (int i = 0; i < 32; i += 4) {
            unsigned int w;
            w  = (unsigned int)g[(size_t)(i + 0) * CC];
            w |= (unsigned int)g[(size_t)(i + 1) * CC] << 8;
            w |= (unsigned int)g[(size_t)(i + 2) * CC] << 16;
            w |= (unsigned int)g[(size_t)(i + 3) * CC] << 24;
            *(unsigned int*)&sCode[c * 144 + r0 + i] = w;
        }
    }

    // ---- stage chunk 0 into buffer 0
    const int lk = tid >> 4;          // 0..15
    const int lm = (tid & 15) * 8;    // halves offset within 128-m tile
#pragma unroll
    for (int l = 0; l < 8; ++l) {
        int rr = lk + l * 16;         // 0..127: (cc*16+k) within chunk
        const uint4 v = *(const uint4*)(Lt + ((size_t)rr * MM + m0 + lm));
        *(uint4*)&sL[0][rr * TM + lm] = v;
    }
    __syncthreads();

    const int mq = tid & 31;          // m-quad: m0 + mq*4 .. +3
    const int rg = tid >> 5;          // row group: rows rg*16 .. +15

    float4 acc[16];
#pragma unroll
    for (int i = 0; i < 16; ++i) acc[i] = make_float4(0.f, 0.f, 0.f, 0.f);

    uint4 pf[8];
    for (int ch = 0; ch < 8; ++ch) {
        if (ch < 7) {                 // prefetch next chunk into regs (in flight during compute)
#pragma unroll
            for (int l = 0; l < 8; ++l) {
                int rr = lk + l * 16;
                pf[l] = *(const uint4*)(Lt + ((size_t)((ch + 1) * 128 + rr) * MM + m0 + lm));
            }
        }
        const __half* buf = sL[ch & 1];
#pragma unroll
        for (int cc = 0; cc < CHUNK; ++cc) {
            int c = ch * CHUNK + cc;
            const uint4 codes = *(const uint4*)&sCode[c * 144 + rg * 16];  // 16 rows' codes, broadcast
            unsigned int cw[4] = {codes.x, codes.y, codes.z, codes.w};
#pragma unroll
            for (int i = 0; i < 16; ++i) {
                int k = (cw[i >> 2] >> ((i & 3) * 8)) & 0xff;
                const unsigned int* p = (const unsigned int*)(buf + ((cc * KK + k) * TM + mq * 4));
                unsigned int u0 = p[0], u1 = p[1];    // ds_read_b64, banks 2mq..2mq+1: 2-way max
                acc[i].x += __half2float(__ushort_as_half((unsigned short)(u0 & 0xffffu)));
                acc[i].y += __half2float(__ushort_as_half((unsigned short)(u0 >> 16)));
                acc[i].z += __half2float(__ushort_as_half((unsigned short)(u1 & 0xffffu)));
                acc[i].w += __half2float(__ushort_as_half((unsigned short)(u1 >> 16)));
            }
        }
        __syncthreads();
        if (ch < 7) {
#pragma unroll
            for (int l = 0; l < 8; ++l) {
                int rr = lk + l * 16;
                *(uint4*)&sL[(ch + 1) & 1][rr * TM + lm] = pf[l];
            }
            __syncthreads();
        }
    }

    // ---- epilogue: coalesced float4 stores
#pragma unroll
    for (int i = 0; i < 16; ++i) {
        int row = j0 + rg * 16 + i;
        *(float4*)(out + (size_t)row * MM + m0 + mq * 4) = acc[i];
    }
}

// ---------------------------------------------------------------------------
extern "C" void kernel_launch(void* const* d_in, const int* in_sizes, int n_in,
                              void* d_out, int out_size, void* d_ws, size_t ws_size,
                              hipStream_t stream) {
    const float* I = (const float*)d_in[0];  // (N, D) fp32
    const float* A = (const float*)d_in[1];  // (C, 8, 4) fp32
    const float* T = (const float*)d_in[2];  // (C*15,) fp32
    const float* L = (const float*)d_in[3];  // (M, C, K) fp32
    // d_in[4] = S, d_in[5] = B: structural constants, hard-coded.

    unsigned char* idx = (unsigned char*)d_ws;                   // 1 MB
    __half* Lt16 = (__half*)((char*)d_ws + (size_t)NN * CC);     // 1 MB, 16B-aligned
    float* out = (float*)d_out;                                  // (N, M) fp32

    hipLaunchKernelGGL(transpose_lut16, dim3((CC * KK * MM) / 256), dim3(256), 0, stream, L, Lt16);
    hipLaunchKernelGGL(encode_kernel, dim3((NN * CC) / 256), dim3(256), 0, stream, I, A, T, idx);
    hipLaunchKernelGGL(decode_kernel, dim3((NN / TR) * (MM / TM)), dim3(256), 0, stream, idx, Lt16, out);
}

// Round 7
// 139.868 us; speedup vs baseline: 1.3220x; 1.3220x over previous
//
#include <hip/hip_runtime.h>
#include <hip/hip_fp16.h>
#include <math.h>

#define CC 64
#define KK 16
#define NNODES 15
#define DD 512      // input feature dim
#define MM 512      // output dim
#define NN 16384    // rows

// ---------------------------------------------------------------------------
// XLA/Eigen fast-tanh for f32 (bit-exact vs JAX's jnp.tanh lowering).
// Round 3/4/5 evidence: required to match the golden's argmax codes.
// ---------------------------------------------------------------------------
__device__ __forceinline__ float xla_tanhf(float x) {
    const float kMax = 7.90531110763549805f;
    bool tiny = fabsf(x) < 0.0004f;
    float xc = fminf(fmaxf(x, -kMax), kMax);
    float x2 = __fmul_rn(xc, xc);
    float p = __fmaf_rn(x2, -2.76076847742355e-16f, 2.00018790482477e-13f);
    p = __fmaf_rn(x2, p, -8.60467152213735e-11f);
    p = __fmaf_rn(x2, p, 5.12229709037114e-08f);
    p = __fmaf_rn(x2, p, 1.48572235717979e-05f);
    p = __fmaf_rn(x2, p, 6.37261928875436e-04f);
    p = __fmaf_rn(x2, p, 4.89352455891786e-03f);
    p = __fmul_rn(xc, p);
    float q = __fmaf_rn(x2, 1.19825839466702e-06f, 1.18534705686654e-04f);
    q = __fmaf_rn(x2, q, 2.26843463243900e-03f);
    q = __fmaf_rn(x2, q, 4.89352518554385e-03f);
    return tiny ? x : __fdiv_rn(p, q);
}

// ---------------------------------------------------------------------------
// Kernel 1: transpose v2 — L (M, C*K) fp32 -> Lt16 (C*K, M) fp16 via LDS
// 64x64 tiles: coalesced global reads AND coalesced 16B global writes
// (round-5/6 version did 1M scattered 2-4B stores — the hidden gap).
// ---------------------------------------------------------------------------
__global__ __launch_bounds__(256) void transpose_lut16(const float* __restrict__ L,
                                                       __half* __restrict__ Lt) {
    __shared__ __half tile[64 * 72];   // [ck_local][m_local], stride 72 (16B-aligned rows)
    const int tid = threadIdx.x;
    const int ck0 = (blockIdx.x & 15) * 64;   // 16 ck-tiles
    const int m0  = (blockIdx.x >> 4) * 64;   // 8 m-tiles

    // read: lanes sweep consecutive ck (coalesced 256B/wave), rows = m
    const int col = tid & 63;
#pragma unroll
    for (int i = 0; i < 16; ++i) {
        int r = (tid >> 6) + i * 4;   // m_local 0..63
        float v = L[(size_t)(m0 + r) * (CC * KK) + ck0 + col];
        tile[col * 72 + r] = __float2half(v);
    }
    __syncthreads();

    // write: 8 lanes per ck-row, 16B each -> contiguous 128B per row
#pragma unroll
    for (int t = 0; t < 2; ++t) {
        int cr   = (tid >> 3) + t * 32;   // ck_local 0..63
        int mseg = (tid & 7) * 8;         // m_local in steps of 8
        uint4 v = *(const uint4*)&tile[cr * 72 + mseg];
        *(uint4*)(Lt + ((size_t)(ck0 + cr) * MM + m0 + mseg)) = v;
    }
}

// ---------------------------------------------------------------------------
// Kernel 2: encode — UNCHANGED (codes verified bit-exact vs golden).
// ---------------------------------------------------------------------------
__global__ __launch_bounds__(256) void encode_kernel(const float* __restrict__ I,
                                                     const float* __restrict__ A,
                                                     const float* __restrict__ T,
                                                     unsigned char* __restrict__ idx) {
    __shared__ float sA[CC * 8 * 4];   // 2048 floats
    __shared__ float sT[CC * NNODES];  // 960 floats
    int tid = threadIdx.x;
    for (int i = tid; i < CC * 32; i += 256) sA[i] = A[i];
    for (int i = tid; i < CC * NNODES; i += 256) sT[i] = T[i];
    __syncthreads();

    int gid = blockIdx.x * 256 + tid;   // 0 .. N*C-1
    int j = gid >> 6;
    int c = gid & 63;

    const float* Ij = I + (size_t)j * DD + c * 8;
    float4 v0 = ((const float4*)Ij)[0];
    float4 v1 = ((const float4*)Ij)[1];
    float iv[8] = {v0.x, v0.y, v0.z, v0.w, v1.x, v1.y, v1.z, v1.w};

    float t[4] = {0.f, 0.f, 0.f, 0.f};
#pragma unroll
    for (int s = 0; s < 8; ++s) {
        float v = iv[s];
#pragma unroll
        for (int d = 0; d < 4; ++d)
            t[d] = __fmaf_rn(v, sA[c * 32 + s * 4 + d], t[d]);
    }

    const int lvl[NNODES] = {0, 1, 1, 2, 2, 2, 2, 3, 3, 3, 3, 3, 3, 3, 3};
    float th[NNODES];
#pragma unroll
    for (int i = 0; i < NNODES; ++i) {
        float h = __fsub_rn(t[lvl[i]], sT[c * NNODES + i]);
        th[i] = xla_tanhf(h);
    }

    int best = 0;
    float bestv = -3.0e38f;
#pragma unroll
    for (int k = 0; k < KK; ++k) {
        int node = 0;
        float s = 0.f;
#pragma unroll
        for (int l = 0; l < 4; ++l) {
            int bit = (k >> (3 - l)) & 1;
            s = __fadd_rn(s, bit ? th[node] : -th[node]);
            node = 2 * node + 1 + bit;
        }
        if (s > bestv) { bestv = s; best = k; }   // strict >: first-max
    }
    idx[gid] = (unsigned char)best;
}

// ---------------------------------------------------------------------------
// Kernel 3: decode v3 — one WAVE per output row, fp16 LUT gathered from L2.
// k is wave-uniform -> scalar-base addressing; each gather is one coalesced
// 1KB global_load_dwordx4 per wave (lane m0 = lane*8 halves). Tiny LDS,
// ~40 VGPRs -> high occupancy; L2-BW-bound at 1.07 GB total.
// Round-6 lesson: keep occupancy, keep per-gather VALU low.
// ---------------------------------------------------------------------------
__global__ __launch_bounds__(256) void decode_kernel(const unsigned char* __restrict__ idx,
                                                     const __half* __restrict__ Lt,
                                                     float* __restrict__ out) {
    __shared__ unsigned char sIdx[4 * CC];
    const int tid = threadIdx.x;
    const int j0 = blockIdx.x * 4;               // 4 rows per block (1/wave)
    sIdx[tid] = idx[(size_t)j0 * CC + tid];      // coalesced 256B
    __syncthreads();

    const int w    = tid >> 6;        // wave = local row
    const int lane = tid & 63;
    const int m0   = lane * 8;        // 8 consecutive m per lane

    float acc[8];
#pragma unroll
    for (int i = 0; i < 8; ++i) acc[i] = 0.f;

#pragma unroll 8
    for (int c = 0; c < CC; ++c) {
        int k = sIdx[w * CC + c];                 // wave-uniform broadcast
        const uint4 v = *(const uint4*)(Lt + ((size_t)((c << 4) + k) * MM + m0));
        acc[0] = __fadd_rn(acc[0], __half2float(__ushort_as_half((unsigned short)(v.x & 0xffffu))));
        acc[1] = __fadd_rn(acc[1], __half2float(__ushort_as_half((unsigned short)(v.x >> 16))));
        acc[2] = __fadd_rn(acc[2], __half2float(__ushort_as_half((unsigned short)(v.y & 0xffffu))));
        acc[3] = __fadd_rn(acc[3], __half2float(__ushort_as_half((unsigned short)(v.y >> 16))));
        acc[4] = __fadd_rn(acc[4], __half2float(__ushort_as_half((unsigned short)(v.z & 0xffffu))));
        acc[5] = __fadd_rn(acc[5], __half2float(__ushort_as_half((unsigned short)(v.z >> 16))));
        acc[6] = __fadd_rn(acc[6], __half2float(__ushort_as_half((unsigned short)(v.w & 0xffffu))));
        acc[7] = __fadd_rn(acc[7], __half2float(__ushort_as_half((unsigned short)(v.w >> 16))));
    }

    float* o = out + (size_t)(j0 + w) * MM + m0;
    *(float4*)(o)     = make_float4(acc[0], acc[1], acc[2], acc[3]);
    *(float4*)(o + 4) = make_float4(acc[4], acc[5], acc[6], acc[7]);
}

// ---------------------------------------------------------------------------
extern "C" void kernel_launch(void* const* d_in, const int* in_sizes, int n_in,
                              void* d_out, int out_size, void* d_ws, size_t ws_size,
                              hipStream_t stream) {
    const float* I = (const float*)d_in[0];  // (N, D) fp32
    const float* A = (const float*)d_in[1];  // (C, 8, 4) fp32
    const float* T = (const float*)d_in[2];  // (C*15,) fp32
    const float* L = (const float*)d_in[3];  // (M, C, K) fp32
    // d_in[4] = S, d_in[5] = B: structural constants, hard-coded.

    unsigned char* idx = (unsigned char*)d_ws;                   // 1 MB
    __half* Lt16 = (__half*)((char*)d_ws + (size_t)NN * CC);     // 1 MB, 16B-aligned
    float* out = (float*)d_out;                                  // (N, M) fp32

    hipLaunchKernelGGL(transpose_lut16, dim3(128), dim3(256), 0, stream, L, Lt16);
    hipLaunchKernelGGL(encode_kernel, dim3((NN * CC) / 256), dim3(256), 0, stream, I, A, T, idx);
    hipLaunchKernelGGL(decode_kernel, dim3(NN / 4), dim3(256), 0, stream, idx, Lt16, out);
}

// Round 8
// 132.783 us; speedup vs baseline: 1.3926x; 1.0534x over previous
//
#include <hip/hip_runtime.h>
#include <hip/hip_fp16.h>
#include <math.h>

#define CC 64
#define KK 16
#define NNODES 15
#define DD 512      // input feature dim
#define MM 512      // output dim
#define NN 16384    // rows

// ---------------------------------------------------------------------------
// XLA/Eigen fast-tanh for f32 (bit-exact vs JAX's jnp.tanh lowering).
// Round 3/4/5 evidence: required to match the golden's argmax codes.
// ---------------------------------------------------------------------------
__device__ __forceinline__ float xla_tanhf(float x) {
    const float kMax = 7.90531110763549805f;
    bool tiny = fabsf(x) < 0.0004f;
    float xc = fminf(fmaxf(x, -kMax), kMax);
    float x2 = __fmul_rn(xc, xc);
    float p = __fmaf_rn(x2, -2.76076847742355e-16f, 2.00018790482477e-13f);
    p = __fmaf_rn(x2, p, -8.60467152213735e-11f);
    p = __fmaf_rn(x2, p, 5.12229709037114e-08f);
    p = __fmaf_rn(x2, p, 1.48572235717979e-05f);
    p = __fmaf_rn(x2, p, 6.37261928875436e-04f);
    p = __fmaf_rn(x2, p, 4.89352455891786e-03f);
    p = __fmul_rn(xc, p);
    float q = __fmaf_rn(x2, 1.19825839466702e-06f, 1.18534705686654e-04f);
    q = __fmaf_rn(x2, q, 2.26843463243900e-03f);
    q = __fmaf_rn(x2, q, 4.89352518554385e-03f);
    return tiny ? x : __fdiv_rn(p, q);
}

// ---------------------------------------------------------------------------
// Kernel 1: transpose — L (M, C*K) fp32 -> Lt16 (C*K, M) fp16 via LDS
// 64x64 tiles: coalesced reads AND coalesced 16B writes. (round-7 verified)
// ---------------------------------------------------------------------------
__global__ __launch_bounds__(256) void transpose_lut16(const float* __restrict__ L,
                                                       __half* __restrict__ Lt) {
    __shared__ __half tile[64 * 72];   // [ck_local][m_local], stride 72
    const int tid = threadIdx.x;
    const int ck0 = (blockIdx.x & 15) * 64;
    const int m0  = (blockIdx.x >> 4) * 64;

    const int col = tid & 63;
#pragma unroll
    for (int i = 0; i < 16; ++i) {
        int r = (tid >> 6) + i * 4;
        float v = L[(size_t)(m0 + r) * (CC * KK) + ck0 + col];
        tile[col * 72 + r] = __float2half(v);
    }
    __syncthreads();

#pragma unroll
    for (int t = 0; t < 2; ++t) {
        int cr   = (tid >> 3) + t * 32;
        int mseg = (tid & 7) * 8;
        uint4 v = *(const uint4*)&tile[cr * 72 + mseg];
        *(uint4*)(Lt + ((size_t)(ck0 + cr) * MM + m0 + mseg)) = v;
    }
}

// ---------------------------------------------------------------------------
// Kernel 2: FUSED encode+decode. 4 rows/block, 1 wave/row.
// Phase 1 (encode): thread (w=tid>>6, c=tid&63) computes row (j0+w)'s code
//   for subspace c — exact round-5 bit-verified math — into LDS.
// Phase 2 (decode): wave w decodes row j0+w: k wave-uniform, each gather is
//   one coalesced 1KB global_load_dwordx4 of the fp16 LUT row (L2-resident).
// Kills: idx global round-trip (1MB w + 1MB r), one launch + its gap, and
// hides encode's ~45%-VALU work under decode's memory waits.
// ---------------------------------------------------------------------------
__global__ __launch_bounds__(256) void fused_kernel(const float* __restrict__ I,
                                                    const float* __restrict__ A,
                                                    const float* __restrict__ T,
                                                    const __half* __restrict__ Lt,
                                                    float* __restrict__ out) {
    __shared__ float sA[CC * 8 * 4];   // 2048 floats
    __shared__ float sT[CC * NNODES];  // 960 floats
    __shared__ unsigned char sIdx[4 * CC];

    const int tid = threadIdx.x;
    for (int i = tid; i < CC * 32; i += 256) sA[i] = A[i];
    for (int i = tid; i < CC * NNODES; i += 256) sT[i] = T[i];
    __syncthreads();

    const int w    = tid >> 6;        // wave = local row
    const int lane = tid & 63;
    const int c    = lane;            // encode subspace
    const int j    = blockIdx.x * 4 + w;

    // ---------------- encode (bit-exact round-5 math) ----------------
    {
        const float* Ij = I + (size_t)j * DD + c * 8;   // wave reads 2KB contiguous
        float4 v0 = ((const float4*)Ij)[0];
        float4 v1 = ((const float4*)Ij)[1];
        float iv[8] = {v0.x, v0.y, v0.z, v0.w, v1.x, v1.y, v1.z, v1.w};

        float t[4] = {0.f, 0.f, 0.f, 0.f};
#pragma unroll
        for (int s = 0; s < 8; ++s) {
            float v = iv[s];
#pragma unroll
            for (int d = 0; d < 4; ++d)
                t[d] = __fmaf_rn(v, sA[c * 32 + s * 4 + d], t[d]);
        }

        const int lvl[NNODES] = {0, 1, 1, 2, 2, 2, 2, 3, 3, 3, 3, 3, 3, 3, 3};
        float th[NNODES];
#pragma unroll
        for (int i = 0; i < NNODES; ++i) {
            float h = __fsub_rn(t[lvl[i]], sT[c * NNODES + i]);
            th[i] = xla_tanhf(h);
        }

        int best = 0;
        float bestv = -3.0e38f;
#pragma unroll
        for (int k = 0; k < KK; ++k) {
            int node = 0;
            float s = 0.f;
#pragma unroll
            for (int l = 0; l < 4; ++l) {
                int bit = (k >> (3 - l)) & 1;
                s = __fadd_rn(s, bit ? th[node] : -th[node]);
                node = 2 * node + 1 + bit;
            }
            if (s > bestv) { bestv = s; best = k; }   // strict >: first-max
        }
        sIdx[tid] = (unsigned char)best;
    }
    __syncthreads();   // cheap insurance; waves arrive nearly together

    // ---------------- decode (round-7 structure, 45.5us verified) ----------------
    const int m0 = lane * 8;          // 8 consecutive m per lane

    float acc[8];
#pragma unroll
    for (int i = 0; i < 8; ++i) acc[i] = 0.f;

#pragma unroll 8
    for (int cc = 0; cc < CC; ++cc) {
        int k = sIdx[w * CC + cc];    // wave-uniform broadcast
        const uint4 v = *(const uint4*)(Lt + ((size_t)((cc << 4) + k) * MM + m0));
        acc[0] = __fadd_rn(acc[0], __half2float(__ushort_as_half((unsigned short)(v.x & 0xffffu))));
        acc[1] = __fadd_rn(acc[1], __half2float(__ushort_as_half((unsigned short)(v.x >> 16))));
        acc[2] = __fadd_rn(acc[2], __half2float(__ushort_as_half((unsigned short)(v.y & 0xffffu))));
        acc[3] = __fadd_rn(acc[3], __half2float(__ushort_as_half((unsigned short)(v.y >> 16))));
        acc[4] = __fadd_rn(acc[4], __half2float(__ushort_as_half((unsigned short)(v.z & 0xffffu))));
        acc[5] = __fadd_rn(acc[5], __half2float(__ushort_as_half((unsigned short)(v.z >> 16))));
        acc[6] = __fadd_rn(acc[6], __half2float(__ushort_as_half((unsigned short)(v.w & 0xffffu))));
        acc[7] = __fadd_rn(acc[7], __half2float(__ushort_as_half((unsigned short)(v.w >> 16))));
    }

    float* o = out + (size_t)j * MM + m0;
    *(float4*)(o)     = make_float4(acc[0], acc[1], acc[2], acc[3]);
    *(float4*)(o + 4) = make_float4(acc[4], acc[5], acc[6], acc[7]);
}

// ---------------------------------------------------------------------------
extern "C" void kernel_launch(void* const* d_in, const int* in_sizes, int n_in,
                              void* d_out, int out_size, void* d_ws, size_t ws_size,
                              hipStream_t stream) {
    const float* I = (const float*)d_in[0];  // (N, D) fp32
    const float* A = (const float*)d_in[1];  // (C, 8, 4) fp32
    const float* T = (const float*)d_in[2];  // (C*15,) fp32
    const float* L = (const float*)d_in[3];  // (M, C, K) fp32
    // d_in[4] = S, d_in[5] = B: structural constants, hard-coded.

    __half* Lt16 = (__half*)d_ws;            // 1 MB fp16 LUT
    float* out = (float*)d_out;              // (N, M) fp32

    hipLaunchKernelGGL(transpose_lut16, dim3(128), dim3(256), 0, stream, L, Lt16);
    hipLaunchKernelGGL(fused_kernel, dim3(NN / 4), dim3(256), 0, stream, I, A, T, Lt16, out);
}